// Round 1
// baseline (609.823 us; speedup 1.0000x reference)
//
#include <hip/hip_runtime.h>
#include <math.h>

// Problem constants (fixed by reference setup_inputs)
constexpr int B = 32, C = 512, N = 1024;   // N = H*W
constexpr int TILE = 64;                    // block tile (64x64)
constexpr int BK = 32;                      // k-tile
constexpr int PADF = 4;                     // row stride 68 floats = 272 B (16B-aligned, breaks pow2 stride)

// ---------------------------------------------------------------------------
// Kernel 1: G[b] = F[b] * F[b]^T  (F = x reshaped [C, N], row-major)
// 64x64 tile, 256 threads, 4x4 micro-tile/thread, LDS stored k-major so the
// fragment reads are contiguous float4 (-> ds_read_b128).
// ---------------------------------------------------------------------------
__global__ __launch_bounds__(256) void gram_kernel(const float* __restrict__ x,
                                                   float* __restrict__ G) {
  const int b  = blockIdx.z;
  const int i0 = blockIdx.y * TILE;
  const int j0 = blockIdx.x * TILE;
  const float* __restrict__ F  = x + (size_t)b * C * N;
  float* __restrict__       Gb = G + (size_t)b * C * C;

  __shared__ float As[BK][TILE + PADF];   // As[kk][i] = F[i0+i][k0+kk]
  __shared__ float Bs[BK][TILE + PADF];   // Bs[kk][j] = F[j0+j][k0+kk]

  const int t  = threadIdx.x;
  const int tx = t & 15, ty = t >> 4;
  const int kk = t & 31, r0 = t >> 5;     // load indexing: 32 contiguous k per row

  float acc[4][4] = {};

  for (int k0 = 0; k0 < N; k0 += BK) {
#pragma unroll
    for (int rr = 0; rr < TILE; rr += 8) {
      const int row = r0 + rr;
      As[kk][row] = F[(size_t)(i0 + row) * N + (k0 + kk)];
      Bs[kk][row] = F[(size_t)(j0 + row) * N + (k0 + kk)];
    }
    __syncthreads();
#pragma unroll
    for (int k = 0; k < BK; ++k) {
      float a[4], bb[4];
#pragma unroll
      for (int i = 0; i < 4; ++i) a[i]  = As[k][ty * 4 + i];
#pragma unroll
      for (int j = 0; j < 4; ++j) bb[j] = Bs[k][tx * 4 + j];
#pragma unroll
      for (int i = 0; i < 4; ++i)
#pragma unroll
        for (int j = 0; j < 4; ++j) acc[i][j] = fmaf(a[i], bb[j], acc[i][j]);
    }
    __syncthreads();
  }

#pragma unroll
  for (int i = 0; i < 4; ++i) {
    const size_t gi = (size_t)(i0 + ty * 4 + i) * C + (j0 + tx * 4);
#pragma unroll
    for (int j = 0; j < 4; ++j) Gb[gi + j] = acc[i][j];
  }
}

// ---------------------------------------------------------------------------
// Kernel 2: in-place row softmax of (rowmax - G) over last dim.
// softmax(M - G)_d = exp(m - G_d) / sum_d exp(m - G_d), m = row MIN of G.
// One 256-thread block per row (C=512 -> 2 elems/thread).
// ---------------------------------------------------------------------------
__global__ __launch_bounds__(256) void softmax_kernel(float* __restrict__ G) {
  float* __restrict__ g = G + (size_t)blockIdx.x * C;
  const int t = threadIdx.x;

  const float v0 = g[t];
  const float v1 = g[t + 256];

  float mn = fminf(v0, v1);
#pragma unroll
  for (int o = 32; o > 0; o >>= 1) mn = fminf(mn, __shfl_down(mn, o, 64));

  __shared__ float redmin[4];
  __shared__ float redsum[4];
  const int wid = t >> 6, lid = t & 63;
  if (lid == 0) redmin[wid] = mn;
  __syncthreads();
  mn = fminf(fminf(redmin[0], redmin[1]), fminf(redmin[2], redmin[3]));

  const float e0 = expf(mn - v0);
  const float e1 = expf(mn - v1);
  float s = e0 + e1;
#pragma unroll
  for (int o = 32; o > 0; o >>= 1) s += __shfl_down(s, o, 64);
  if (lid == 0) redsum[wid] = s;
  __syncthreads();
  s = redsum[0] + redsum[1] + redsum[2] + redsum[3];

  const float inv = 1.0f / s;
  g[t]       = e0 * inv;
  g[t + 256] = e1 * inv;
}

// ---------------------------------------------------------------------------
// Kernel 3: E = A * F, out = beta * E + x.   A=[C,C], F=[C,N], both row-major.
// Same tiling; A is transposed into k-major LDS on load, F loaded naturally.
// ---------------------------------------------------------------------------
__global__ __launch_bounds__(256) void av_kernel(const float* __restrict__ Attn,
                                                 const float* __restrict__ x,
                                                 const float* __restrict__ beta,
                                                 float* __restrict__ out) {
  const int b  = blockIdx.z;
  const int i0 = blockIdx.y * TILE;   // over C
  const int j0 = blockIdx.x * TILE;   // over N
  const float* __restrict__ Ab = Attn + (size_t)b * C * C;
  const float* __restrict__ F  = x    + (size_t)b * C * N;
  float* __restrict__       Ob = out  + (size_t)b * C * N;

  __shared__ float As[BK][TILE + PADF];   // As[kk][i] = A[i0+i][k0+kk]
  __shared__ float Bs[BK][TILE + PADF];   // Bs[kk][j] = F[k0+kk][j0+j]

  const int t   = threadIdx.x;
  const int tx  = t & 15, ty = t >> 4;
  const int kkA = t & 31, rA = t >> 5;
  const int jB  = t & 63, kB = t >> 6;

  float acc[4][4] = {};

  for (int k0 = 0; k0 < C; k0 += BK) {
#pragma unroll
    for (int rr = 0; rr < TILE; rr += 8)
      As[kkA][rA + rr] = Ab[(size_t)(i0 + rA + rr) * C + (k0 + kkA)];
#pragma unroll
    for (int kc = 0; kc < BK; kc += 4)
      Bs[kB + kc][jB] = F[(size_t)(k0 + kB + kc) * N + (j0 + jB)];
    __syncthreads();
#pragma unroll
    for (int k = 0; k < BK; ++k) {
      float a[4], bb[4];
#pragma unroll
      for (int i = 0; i < 4; ++i) a[i]  = As[k][ty * 4 + i];
#pragma unroll
      for (int j = 0; j < 4; ++j) bb[j] = Bs[k][tx * 4 + j];
#pragma unroll
      for (int i = 0; i < 4; ++i)
#pragma unroll
        for (int j = 0; j < 4; ++j) acc[i][j] = fmaf(a[i], bb[j], acc[i][j]);
    }
    __syncthreads();
  }

  const float bv = beta[0];
#pragma unroll
  for (int i = 0; i < 4; ++i) {
    const size_t o = (size_t)(i0 + ty * 4 + i) * N + (j0 + tx * 4);
#pragma unroll
    for (int j = 0; j < 4; ++j) Ob[o + j] = fmaf(bv, acc[i][j], F[o + j]);
  }
}

// ---------------------------------------------------------------------------
extern "C" void kernel_launch(void* const* d_in, const int* in_sizes, int n_in,
                              void* d_out, int out_size, void* d_ws, size_t ws_size,
                              hipStream_t stream) {
  const float* x    = (const float*)d_in[0];
  const float* beta = (const float*)d_in[1];
  float* out = (float*)d_out;
  float* G   = (float*)d_ws;              // B*C*C floats = 32 MB scratch

  const dim3 blk(256);
  gram_kernel   <<<dim3(C / TILE, C / TILE, B), blk, 0, stream>>>(x, G);
  softmax_kernel<<<dim3(B * C),                 blk, 0, stream>>>(G);
  av_kernel     <<<dim3(N / TILE, C / TILE, B), blk, 0, stream>>>(G, x, beta, out);
}

// Round 2
// 283.355 us; speedup vs baseline: 2.1522x; 2.1522x over previous
//
#include <hip/hip_runtime.h>
#include <math.h>

// Problem constants (fixed by reference setup_inputs)
constexpr int B = 32, C = 512, N = 1024;   // N = H*W

typedef float f32x4 __attribute__((ext_vector_type(4)));
typedef short s16x8 __attribute__((ext_vector_type(8)));

// bf16 bit helpers (RNE), no dependence on hip_bf16 API details
__device__ __forceinline__ unsigned short f32_to_bf16(float v) {
  union { float f; unsigned u; } a; a.f = v;
  unsigned r = (a.u + 0x7FFFu + ((a.u >> 16) & 1u)) >> 16;
  return (unsigned short)r;
}
__device__ __forceinline__ float bf16_to_f32(unsigned short h) {
  union { float f; unsigned u; } a; a.u = ((unsigned)h) << 16;
  return a.f;
}

// async global->LDS, 16B per lane; LDS dest = wave-uniform base + lane*16
__device__ __forceinline__ void glds16(const void* g, void* l) {
  __builtin_amdgcn_global_load_lds((const __attribute__((address_space(1))) void*)g,
                                   (__attribute__((address_space(3))) void*)l, 16, 0, 0);
}

// ---------------------------------------------------------------------------
// Kernel 0: split x (fp32 [B,C,N]) into bf16 hi, lo, and transposed hi [B,N,C].
// 32x32 tiles, LDS transpose for coalesced xhT writes.
// ---------------------------------------------------------------------------
__global__ __launch_bounds__(256) void convert_kernel(const float* __restrict__ x,
                                                      unsigned short* __restrict__ xh,
                                                      unsigned short* __restrict__ xl,
                                                      unsigned short* __restrict__ xhT) {
  const int b = blockIdx.z, by = blockIdx.y, bx = blockIdx.x;
  const int t = threadIdx.x, r = t >> 5, c = t & 31;
  __shared__ unsigned short T[32][33];
  const size_t xbase = ((size_t)b * C + by * 32) * N + bx * 32;
#pragma unroll
  for (int rr = 0; rr < 32; rr += 8) {
    const int row = rr + r;
    const size_t gi = xbase + (size_t)row * N + c;
    const float v = x[gi];
    const unsigned short hb = f32_to_bf16(v);
    const unsigned short lb = f32_to_bf16(v - bf16_to_f32(hb));
    xh[gi] = hb;
    xl[gi] = lb;
    T[row][c] = hb;
  }
  __syncthreads();
  const size_t tbase = ((size_t)b * N + bx * 32) * C + by * 32;
#pragma unroll
  for (int rr = 0; rr < 32; rr += 8) {
    const int nrow = rr + r;
    xhT[tbase + (size_t)nrow * C + c] = T[c][nrow];
  }
}

// ---------------------------------------------------------------------------
// Kernel 1: G[b] = F*F^T in split bf16: hi*hi^T + hi*lo^T + lo*hi^T.
// 128x128 block tile, BK=32, 256 thr (4 waves, each a 64x64 subtile = 4x4
// mfma_f32_16x16x32_bf16 tiles). Staging via global_load_lds width 16.
// ---------------------------------------------------------------------------
__global__ __launch_bounds__(256) void gram_mfma(const unsigned short* __restrict__ xh,
                                                 const unsigned short* __restrict__ xl,
                                                 float* __restrict__ G) {
  const int b = blockIdx.z;
  const int i0 = blockIdx.y * 128, j0 = blockIdx.x * 128;
  const unsigned short* __restrict__ Fh = xh + (size_t)b * C * N;
  const unsigned short* __restrict__ Fl = xl + (size_t)b * C * N;
  float* __restrict__ Gb = G + (size_t)b * C * C;

  // unpadded row-major [128][32] bf16 tiles (global_load_lds layout constraint)
  __shared__ __align__(16) unsigned short Ah[128 * 32], Al[128 * 32],
                                          Bh[128 * 32], Bl[128 * 32];

  const int t = threadIdx.x, wave = t >> 6, lane = t & 63;
  const int wi = wave >> 1, wj = wave & 1;
  const int lrow = lane & 15, quad = lane >> 4;
  const int crow = lane >> 2;          // row within 16-row staging chunk
  const int kel  = (lane & 3) * 8;     // bf16-element offset within row

  f32x4 acc_hh[4][4] = {};
  f32x4 acc_x[4][4]  = {};

  for (int k0 = 0; k0 < N; k0 += 32) {
    __syncthreads();   // previous iter's LDS reads done
#pragma unroll
    for (int cc = 0; cc < 2; ++cc) {
      const int chunk = wave * 2 + cc;          // 8 chunks of 16 rows
      const int row = chunk * 16 + crow;
      const size_t gA = (size_t)(i0 + row) * N + k0 + kel;
      const size_t gB = (size_t)(j0 + row) * N + k0 + kel;
      glds16(Fh + gA, &Ah[chunk * 512]);
      glds16(Fl + gA, &Al[chunk * 512]);
      glds16(Fh + gB, &Bh[chunk * 512]);
      glds16(Fl + gB, &Bl[chunk * 512]);
    }
    __syncthreads();   // staging visible

    s16x8 ah[4], al[4], bh[4], bl[4];
#pragma unroll
    for (int ti = 0; ti < 4; ++ti) {
      const int r = (wi * 64 + ti * 16 + lrow) * 32 + quad * 8;
      ah[ti] = *(const s16x8*)&Ah[r];
      al[ti] = *(const s16x8*)&Al[r];
    }
#pragma unroll
    for (int tj = 0; tj < 4; ++tj) {
      const int r = (wj * 64 + tj * 16 + lrow) * 32 + quad * 8;
      bh[tj] = *(const s16x8*)&Bh[r];
      bl[tj] = *(const s16x8*)&Bl[r];
    }
#pragma unroll
    for (int ti = 0; ti < 4; ++ti)
#pragma unroll
      for (int tj = 0; tj < 4; ++tj) {
        acc_hh[ti][tj] = __builtin_amdgcn_mfma_f32_16x16x32_bf16(ah[ti], bh[tj], acc_hh[ti][tj], 0, 0, 0);
        acc_x[ti][tj]  = __builtin_amdgcn_mfma_f32_16x16x32_bf16(ah[ti], bl[tj], acc_x[ti][tj], 0, 0, 0);
        acc_x[ti][tj]  = __builtin_amdgcn_mfma_f32_16x16x32_bf16(al[ti], bh[tj], acc_x[ti][tj], 0, 0, 0);
      }
  }

  // C/D layout: col = lane&15, row = quad*4 + reg  [measured m89]
#pragma unroll
  for (int ti = 0; ti < 4; ++ti) {
    const int gr0 = i0 + wi * 64 + ti * 16 + quad * 4;
#pragma unroll
    for (int tj = 0; tj < 4; ++tj) {
      const int gc = j0 + wj * 64 + tj * 16 + lrow;
#pragma unroll
      for (int r = 0; r < 4; ++r)
        Gb[(size_t)(gr0 + r) * C + gc] = acc_hh[ti][tj][r] + acc_x[ti][tj][r];
    }
  }
}

// ---------------------------------------------------------------------------
// Kernel 2: row softmax of (rowmax - G) == exp(rowmin - G)/sum, output bf16.
// ---------------------------------------------------------------------------
__global__ __launch_bounds__(256) void softmax_kernel(const float* __restrict__ G,
                                                      unsigned short* __restrict__ A) {
  const float* __restrict__ g = G + (size_t)blockIdx.x * C;
  unsigned short* __restrict__ a = A + (size_t)blockIdx.x * C;
  const int t = threadIdx.x;

  const float v0 = g[t];
  const float v1 = g[t + 256];

  float mn = fminf(v0, v1);
#pragma unroll
  for (int o = 32; o > 0; o >>= 1) mn = fminf(mn, __shfl_xor(mn, o, 64));

  __shared__ float redmin[4];
  __shared__ float redsum[4];
  const int wid = t >> 6, lid = t & 63;
  if (lid == 0) redmin[wid] = mn;
  __syncthreads();
  mn = fminf(fminf(redmin[0], redmin[1]), fminf(redmin[2], redmin[3]));

  const float e0 = __expf(mn - v0);
  const float e1 = __expf(mn - v1);
  float s = e0 + e1;
#pragma unroll
  for (int o = 32; o > 0; o >>= 1) s += __shfl_xor(s, o, 64);
  if (lid == 0) redsum[wid] = s;
  __syncthreads();
  s = redsum[0] + redsum[1] + redsum[2] + redsum[3];

  const float inv = 1.0f / s;
  a[t]       = f32_to_bf16(e0 * inv);
  a[t + 256] = f32_to_bf16(e1 * inv);
}

// ---------------------------------------------------------------------------
// Kernel 3: E = A*F (plain bf16 MFMA), out = beta*E + x.
// A [C,C] row-major bf16; F^T [N,C] bf16 so both frags are row-contiguous.
// ---------------------------------------------------------------------------
__global__ __launch_bounds__(256) void av_mfma(const unsigned short* __restrict__ Abf,
                                               const unsigned short* __restrict__ xhT,
                                               const float* __restrict__ x,
                                               const float* __restrict__ beta,
                                               float* __restrict__ out) {
  const int b = blockIdx.z;
  const int i0 = blockIdx.y * 128;   // over C
  const int j0 = blockIdx.x * 128;   // over N
  const unsigned short* __restrict__ Ab = Abf + (size_t)b * C * C;
  const unsigned short* __restrict__ FT = xhT + (size_t)b * N * C;
  const float* __restrict__ xb = x + (size_t)b * C * N;
  float* __restrict__ ob = out + (size_t)b * C * N;

  __shared__ __align__(16) unsigned short As[128 * 32], Bs[128 * 32];

  const int t = threadIdx.x, wave = t >> 6, lane = t & 63;
  const int wi = wave >> 1, wj = wave & 1;
  const int lrow = lane & 15, quad = lane >> 4;
  const int crow = lane >> 2;
  const int kel  = (lane & 3) * 8;

  f32x4 acc[4][4] = {};

  for (int k0 = 0; k0 < C; k0 += 32) {
    __syncthreads();
#pragma unroll
    for (int cc = 0; cc < 2; ++cc) {
      const int chunk = wave * 2 + cc;
      const int row = chunk * 16 + crow;
      glds16(Ab + (size_t)(i0 + row) * C + k0 + kel, &As[chunk * 512]);
      glds16(FT + (size_t)(j0 + row) * C + k0 + kel, &Bs[chunk * 512]);
    }
    __syncthreads();

    s16x8 af[4], bf[4];
#pragma unroll
    for (int ti = 0; ti < 4; ++ti)
      af[ti] = *(const s16x8*)&As[(wi * 64 + ti * 16 + lrow) * 32 + quad * 8];
#pragma unroll
    for (int tj = 0; tj < 4; ++tj)
      bf[tj] = *(const s16x8*)&Bs[(wj * 64 + tj * 16 + lrow) * 32 + quad * 8];

#pragma unroll
    for (int ti = 0; ti < 4; ++ti)
#pragma unroll
      for (int tj = 0; tj < 4; ++tj)
        acc[ti][tj] = __builtin_amdgcn_mfma_f32_16x16x32_bf16(af[ti], bf[tj], acc[ti][tj], 0, 0, 0);
  }

  const float bv = beta[0];
#pragma unroll
  for (int ti = 0; ti < 4; ++ti) {
    const int gr0 = i0 + wi * 64 + ti * 16 + quad * 4;
#pragma unroll
    for (int tj = 0; tj < 4; ++tj) {
      const int gc = j0 + wj * 64 + tj * 16 + lrow;
#pragma unroll
      for (int r = 0; r < 4; ++r) {
        const size_t o = (size_t)(gr0 + r) * N + gc;
        ob[o] = fmaf(bv, acc[ti][tj][r], xb[o]);
      }
    }
  }
}

// ---------------------------------------------------------------------------
extern "C" void kernel_launch(void* const* d_in, const int* in_sizes, int n_in,
                              void* d_out, int out_size, void* d_ws, size_t ws_size,
                              hipStream_t stream) {
  const float* x    = (const float*)d_in[0];
  const float* beta = (const float*)d_in[1];
  float* out = (float*)d_out;

  char* ws = (char*)d_ws;
  float* G            = (float*)ws;                 ws += (size_t)B * C * C * 4;  // 32 MB
  unsigned short* xh  = (unsigned short*)ws;        ws += (size_t)B * C * N * 2;  // 32 MB
  unsigned short* xl  = (unsigned short*)ws;        ws += (size_t)B * C * N * 2;  // 32 MB
  unsigned short* xhT = (unsigned short*)ws;        ws += (size_t)B * N * C * 2;  // 32 MB
  unsigned short* Abf = (unsigned short*)ws;                                      // 16 MB

  const dim3 blk(256);
  convert_kernel<<<dim3(N / 32, C / 32, B),   blk, 0, stream>>>(x, xh, xl, xhT);
  gram_mfma     <<<dim3(C / 128, C / 128, B), blk, 0, stream>>>(xh, xl, G);
  softmax_kernel<<<dim3(B * C),               blk, 0, stream>>>(G, Abf);
  av_mfma       <<<dim3(N / 128, C / 128, B), blk, 0, stream>>>(Abf, xhT, x, beta, out);
}

// Round 3
// 245.876 us; speedup vs baseline: 2.4802x; 1.1524x over previous
//
#include <hip/hip_runtime.h>
#include <math.h>

// Problem constants (fixed by reference setup_inputs)
constexpr int B = 32, C = 512, N = 1024;   // N = H*W

typedef float f32x4 __attribute__((ext_vector_type(4)));
typedef short s16x8 __attribute__((ext_vector_type(8)));
typedef unsigned short u16x4 __attribute__((ext_vector_type(4)));

// bf16 bit helpers (RNE)
__device__ __forceinline__ unsigned short f32_to_bf16(float v) {
  union { float f; unsigned u; } a; a.f = v;
  unsigned r = (a.u + 0x7FFFu + ((a.u >> 16) & 1u)) >> 16;
  return (unsigned short)r;
}
__device__ __forceinline__ float bf16_to_f32(unsigned short h) {
  union { float f; unsigned u; } a; a.u = ((unsigned)h) << 16;
  return a.f;
}

// async global->LDS, 16B per lane; LDS dest = wave-uniform base + lane*16
__device__ __forceinline__ void glds16(const void* g, void* l) {
  __builtin_amdgcn_global_load_lds((const __attribute__((address_space(1))) void*)g,
                                   (__attribute__((address_space(3))) void*)l, 16, 0, 0);
}

// ---------------------------------------------------------------------------
// Kernel 0: split x (fp32 [B,C,N]) into bf16 hi, lo, and transposed hi [B,N,C].
// 64x64 tiles; float4 loads, ushort4 stores; LDS transpose for xhT.
// ---------------------------------------------------------------------------
__global__ __launch_bounds__(256) void convert_kernel(const float* __restrict__ x,
                                                      unsigned short* __restrict__ xh,
                                                      unsigned short* __restrict__ xl,
                                                      unsigned short* __restrict__ xhT) {
  const int b = blockIdx.z;
  const int cy = blockIdx.y * 64;   // C tile origin
  const int nx = blockIdx.x * 64;   // N tile origin
  const int t = threadIdx.x;
  const int r = t >> 4, c4 = (t & 15) * 4;

  __shared__ unsigned short T[64][68];

#pragma unroll
  for (int rr = 0; rr < 64; rr += 16) {
    const int row = rr + r;
    const size_t gi = ((size_t)b * C + cy + row) * N + nx + c4;
    const float4 v = *(const float4*)&x[gi];
    u16x4 h, l;
    h[0] = f32_to_bf16(v.x); l[0] = f32_to_bf16(v.x - bf16_to_f32(h[0]));
    h[1] = f32_to_bf16(v.y); l[1] = f32_to_bf16(v.y - bf16_to_f32(h[1]));
    h[2] = f32_to_bf16(v.z); l[2] = f32_to_bf16(v.z - bf16_to_f32(h[2]));
    h[3] = f32_to_bf16(v.w); l[3] = f32_to_bf16(v.w - bf16_to_f32(h[3]));
    *(u16x4*)&xh[gi] = h;
    *(u16x4*)&xl[gi] = l;
    T[row][c4 + 0] = h[0]; T[row][c4 + 1] = h[1];
    T[row][c4 + 2] = h[2]; T[row][c4 + 3] = h[3];
  }
  __syncthreads();
#pragma unroll
  for (int rr = 0; rr < 64; rr += 16) {
    const int nrow = rr + r;           // N-index within tile
    u16x4 o;
    o[0] = T[c4 + 0][nrow]; o[1] = T[c4 + 1][nrow];
    o[2] = T[c4 + 2][nrow]; o[3] = T[c4 + 3][nrow];
    *(u16x4*)&xhT[((size_t)b * N + nx + nrow) * C + cy + c4] = o;
  }
}

// ---------------------------------------------------------------------------
// Kernel 1: G[b] = F*F^T split bf16: hi*hi^T + hi*lo^T + lo*hi^T, chained into
// ONE accumulator. 128x128 tile, BK=32, 512 threads = 8 waves (4x2), each wave
// a 32x64 subtile (2x4 mfma_f32_16x16x32_bf16 tiles). global_load_lds staging.
// ---------------------------------------------------------------------------
__global__ __launch_bounds__(512, 4) void gram_mfma(const unsigned short* __restrict__ xh,
                                                    const unsigned short* __restrict__ xl,
                                                    float* __restrict__ G) {
  const int b = blockIdx.z;
  const int i0 = blockIdx.y * 128, j0 = blockIdx.x * 128;
  const unsigned short* __restrict__ Fh = xh + (size_t)b * C * N;
  const unsigned short* __restrict__ Fl = xl + (size_t)b * C * N;
  float* __restrict__ Gb = G + (size_t)b * C * C;

  // unpadded row-major [128][32] bf16 tiles (global_load_lds layout constraint)
  __shared__ __align__(16) unsigned short Ah[128 * 32], Al[128 * 32],
                                          Bh[128 * 32], Bl[128 * 32];

  const int t = threadIdx.x, wave = t >> 6, lane = t & 63;
  const int wi = wave >> 1, wj = wave & 1;    // 4x2 wave grid
  const int lrow = lane & 15, quad = lane >> 4;
  const int srow = wave * 16 + (lane >> 2);   // staging row (8 waves x 16 rows)
  const int sel  = (lane & 3) * 8;            // staging bf16-element offset

  f32x4 acc[2][4] = {};

  for (int k0 = 0; k0 < N; k0 += 32) {
    __syncthreads();   // previous iter's LDS reads done
    {
      const size_t gA = (size_t)(i0 + srow) * N + k0 + sel;
      const size_t gB = (size_t)(j0 + srow) * N + k0 + sel;
      glds16(Fh + gA, &Ah[wave * 512]);
      glds16(Fl + gA, &Al[wave * 512]);
      glds16(Fh + gB, &Bh[wave * 512]);
      glds16(Fl + gB, &Bl[wave * 512]);
    }
    __syncthreads();   // staging visible

    s16x8 ah[2], al[2], bh[4], bl[4];
#pragma unroll
    for (int ti = 0; ti < 2; ++ti) {
      const int r = (wi * 32 + ti * 16 + lrow) * 32 + quad * 8;
      ah[ti] = *(const s16x8*)&Ah[r];
      al[ti] = *(const s16x8*)&Al[r];
    }
#pragma unroll
    for (int tj = 0; tj < 4; ++tj) {
      const int r = (wj * 64 + tj * 16 + lrow) * 32 + quad * 8;
      bh[tj] = *(const s16x8*)&Bh[r];
      bl[tj] = *(const s16x8*)&Bl[r];
    }
#pragma unroll
    for (int ti = 0; ti < 2; ++ti)
#pragma unroll
      for (int tj = 0; tj < 4; ++tj) {
        acc[ti][tj] = __builtin_amdgcn_mfma_f32_16x16x32_bf16(ah[ti], bh[tj], acc[ti][tj], 0, 0, 0);
        acc[ti][tj] = __builtin_amdgcn_mfma_f32_16x16x32_bf16(ah[ti], bl[tj], acc[ti][tj], 0, 0, 0);
        acc[ti][tj] = __builtin_amdgcn_mfma_f32_16x16x32_bf16(al[ti], bh[tj], acc[ti][tj], 0, 0, 0);
      }
  }

  // C/D layout: col = lane&15, row = quad*4 + reg  [measured m89]
#pragma unroll
  for (int ti = 0; ti < 2; ++ti) {
    const int gr0 = i0 + wi * 32 + ti * 16 + quad * 4;
#pragma unroll
    for (int tj = 0; tj < 4; ++tj) {
      const int gc = j0 + wj * 64 + tj * 16 + lrow;
#pragma unroll
      for (int r = 0; r < 4; ++r)
        Gb[(size_t)(gr0 + r) * C + gc] = acc[ti][tj][r];
    }
  }
}

// ---------------------------------------------------------------------------
// Kernel 2: row softmax of (rowmax - G) == exp(rowmin - G)/sum, output bf16.
// 2 rows per 256-thread block; float4 reads, ushort4 writes.
// ---------------------------------------------------------------------------
__global__ __launch_bounds__(256) void softmax_kernel(const float* __restrict__ G,
                                                      unsigned short* __restrict__ A) {
  const int t = threadIdx.x;
  const int r = t >> 7;               // row within block (0/1)
  const int c = t & 127;              // float4 index (128 * 4 = 512 = C)
  const size_t row = (size_t)blockIdx.x * 2 + r;

  const float4 v = *(const float4*)&G[row * C + c * 4];
  float mn = fminf(fminf(v.x, v.y), fminf(v.z, v.w));
#pragma unroll
  for (int o = 32; o > 0; o >>= 1) mn = fminf(mn, __shfl_xor(mn, o, 64));

  __shared__ float redmin[4], redsum[4];
  const int w = t >> 6;
  if ((t & 63) == 0) redmin[w] = mn;
  __syncthreads();
  mn = fminf(redmin[r * 2], redmin[r * 2 + 1]);

  const float e0 = __expf(mn - v.x), e1 = __expf(mn - v.y);
  const float e2 = __expf(mn - v.z), e3 = __expf(mn - v.w);
  float s = e0 + e1 + e2 + e3;
#pragma unroll
  for (int o = 32; o > 0; o >>= 1) s += __shfl_xor(s, o, 64);
  if ((t & 63) == 0) redsum[w] = s;
  __syncthreads();
  s = redsum[r * 2] + redsum[r * 2 + 1];

  const float inv = 1.0f / s;
  u16x4 o4;
  o4[0] = f32_to_bf16(e0 * inv); o4[1] = f32_to_bf16(e1 * inv);
  o4[2] = f32_to_bf16(e2 * inv); o4[3] = f32_to_bf16(e3 * inv);
  *(u16x4*)&A[row * C + c * 4] = o4;
}

// ---------------------------------------------------------------------------
// Kernel 3: E = A*F (plain bf16 MFMA), out = beta*E + x.
// A [C,C] row-major bf16; F^T [N,C] bf16 so both frags are row-contiguous.
// 128x128 tile, 256 threads (4 waves, each 64x64).
// ---------------------------------------------------------------------------
__global__ __launch_bounds__(256, 4) void av_mfma(const unsigned short* __restrict__ Abf,
                                                  const unsigned short* __restrict__ xhT,
                                                  const float* __restrict__ x,
                                                  const float* __restrict__ beta,
                                                  float* __restrict__ out) {
  const int b = blockIdx.z;
  const int i0 = blockIdx.y * 128;   // over C
  const int j0 = blockIdx.x * 128;   // over N
  const unsigned short* __restrict__ Ab = Abf + (size_t)b * C * C;
  const unsigned short* __restrict__ FT = xhT + (size_t)b * N * C;
  const float* __restrict__ xb = x + (size_t)b * C * N;
  float* __restrict__ ob = out + (size_t)b * C * N;

  __shared__ __align__(16) unsigned short As[128 * 32], Bs[128 * 32];

  const int t = threadIdx.x, wave = t >> 6, lane = t & 63;
  const int wi = wave >> 1, wj = wave & 1;
  const int lrow = lane & 15, quad = lane >> 4;
  const int crow = lane >> 2;
  const int kel  = (lane & 3) * 8;

  f32x4 acc[4][4] = {};

  for (int k0 = 0; k0 < C; k0 += 32) {
    __syncthreads();
#pragma unroll
    for (int cc = 0; cc < 2; ++cc) {
      const int chunk = wave * 2 + cc;
      const int row = chunk * 16 + crow;
      glds16(Ab + (size_t)(i0 + row) * C + k0 + kel, &As[chunk * 512]);
      glds16(FT + (size_t)(j0 + row) * C + k0 + kel, &Bs[chunk * 512]);
    }
    __syncthreads();

    s16x8 af[4], bf[4];
#pragma unroll
    for (int ti = 0; ti < 4; ++ti)
      af[ti] = *(const s16x8*)&As[(wi * 64 + ti * 16 + lrow) * 32 + quad * 8];
#pragma unroll
    for (int tj = 0; tj < 4; ++tj)
      bf[tj] = *(const s16x8*)&Bs[(wj * 64 + tj * 16 + lrow) * 32 + quad * 8];

#pragma unroll
    for (int ti = 0; ti < 4; ++ti)
#pragma unroll
      for (int tj = 0; tj < 4; ++tj)
        acc[ti][tj] = __builtin_amdgcn_mfma_f32_16x16x32_bf16(af[ti], bf[tj], acc[ti][tj], 0, 0, 0);
  }

  const float bv = beta[0];
#pragma unroll
  for (int ti = 0; ti < 4; ++ti) {
    const int gr0 = i0 + wi * 64 + ti * 16 + quad * 4;
#pragma unroll
    for (int tj = 0; tj < 4; ++tj) {
      const int gc = j0 + wj * 64 + tj * 16 + lrow;
#pragma unroll
      for (int r = 0; r < 4; ++r) {
        const size_t o = (size_t)(gr0 + r) * N + gc;
        ob[o] = fmaf(bv, acc[ti][tj][r], xb[o]);
      }
    }
  }
}

// ---------------------------------------------------------------------------
extern "C" void kernel_launch(void* const* d_in, const int* in_sizes, int n_in,
                              void* d_out, int out_size, void* d_ws, size_t ws_size,
                              hipStream_t stream) {
  const float* x    = (const float*)d_in[0];
  const float* beta = (const float*)d_in[1];
  float* out = (float*)d_out;

  char* ws = (char*)d_ws;
  float* G            = (float*)ws;          ws += (size_t)B * C * C * 4;  // 32 MB
  unsigned short* xh  = (unsigned short*)ws; ws += (size_t)B * C * N * 2;  // 32 MB
  unsigned short* xl  = (unsigned short*)ws; ws += (size_t)B * C * N * 2;  // 32 MB
  unsigned short* xhT = (unsigned short*)ws; ws += (size_t)B * N * C * 2;  // 32 MB
  unsigned short* Abf = (unsigned short*)ws;                               // 16 MB

  convert_kernel<<<dim3(N / 64, C / 64, B),   dim3(256), 0, stream>>>(x, xh, xl, xhT);
  gram_mfma     <<<dim3(C / 128, C / 128, B), dim3(512), 0, stream>>>(xh, xl, G);
  softmax_kernel<<<dim3(B * C / 2),           dim3(256), 0, stream>>>(G, Abf);
  av_mfma       <<<dim3(N / 128, C / 128, B), dim3(256), 0, stream>>>(Abf, xhT, x, beta, out);
}

// Round 4
// 205.157 us; speedup vs baseline: 2.9725x; 1.1985x over previous
//
#include <hip/hip_runtime.h>
#include <math.h>

// Problem constants (fixed by reference setup_inputs)
constexpr int B = 32, C = 512, N = 1024;   // N = H*W

typedef float f32x4 __attribute__((ext_vector_type(4)));
typedef short s16x8 __attribute__((ext_vector_type(8)));
typedef unsigned short u16x4 __attribute__((ext_vector_type(4)));

// bf16 bit helpers (RNE)
__device__ __forceinline__ unsigned short f32_to_bf16(float v) {
  union { float f; unsigned u; } a; a.f = v;
  unsigned r = (a.u + 0x7FFFu + ((a.u >> 16) & 1u)) >> 16;
  return (unsigned short)r;
}
__device__ __forceinline__ float bf16_to_f32(unsigned short h) {
  union { float f; unsigned u; } a; a.u = ((unsigned)h) << 16;
  return a.f;
}

// async global->LDS, 16B per lane; LDS dest = wave-uniform base + lane*16
__device__ __forceinline__ void glds16(const void* g, void* l) {
  __builtin_amdgcn_global_load_lds((const __attribute__((address_space(1))) void*)g,
                                   (__attribute__((address_space(3))) void*)l, 16, 0, 0);
}

// ---------------------------------------------------------------------------
// Kernel 0: split x (fp32 [B,C,N]) into bf16 hi, lo, and transposed hi [B,N,C].
// ---------------------------------------------------------------------------
__global__ __launch_bounds__(256) void convert_kernel(const float* __restrict__ x,
                                                      unsigned short* __restrict__ xh,
                                                      unsigned short* __restrict__ xl,
                                                      unsigned short* __restrict__ xhT) {
  const int b = blockIdx.z;
  const int cy = blockIdx.y * 64;   // C tile origin
  const int nx = blockIdx.x * 64;   // N tile origin
  const int t = threadIdx.x;
  const int r = t >> 4, c4 = (t & 15) * 4;

  __shared__ unsigned short T[64][68];

#pragma unroll
  for (int rr = 0; rr < 64; rr += 16) {
    const int row = rr + r;
    const size_t gi = ((size_t)b * C + cy + row) * N + nx + c4;
    const float4 v = *(const float4*)&x[gi];
    u16x4 h, l;
    h[0] = f32_to_bf16(v.x); l[0] = f32_to_bf16(v.x - bf16_to_f32(h[0]));
    h[1] = f32_to_bf16(v.y); l[1] = f32_to_bf16(v.y - bf16_to_f32(h[1]));
    h[2] = f32_to_bf16(v.z); l[2] = f32_to_bf16(v.z - bf16_to_f32(h[2]));
    h[3] = f32_to_bf16(v.w); l[3] = f32_to_bf16(v.w - bf16_to_f32(h[3]));
    *(u16x4*)&xh[gi] = h;
    *(u16x4*)&xl[gi] = l;
    T[row][c4 + 0] = h[0]; T[row][c4 + 1] = h[1];
    T[row][c4 + 2] = h[2]; T[row][c4 + 3] = h[3];
  }
  __syncthreads();
#pragma unroll
  for (int rr = 0; rr < 64; rr += 16) {
    const int nrow = rr + r;
    u16x4 o;
    o[0] = T[c4 + 0][nrow]; o[1] = T[c4 + 1][nrow];
    o[2] = T[c4 + 2][nrow]; o[3] = T[c4 + 3][nrow];
    *(u16x4*)&xhT[((size_t)b * N + nx + nrow) * C + cy + c4] = o;
  }
}

// ---------------------------------------------------------------------------
// Kernel 1: G = F*F^T split bf16 (hi*hi + hi*lo + lo*hi chained).
// 128x128 tile, BK=64, 512 threads (8 waves, 4x2; each wave 32x64 = 2x4 MFMA).
// XOR k-group swizzle on the GLOBAL source address so LDS storage slot is
// g^row -> ds_read_b128 stays at its 8-phase floor despite 128B rows.
// 1D grid with batch->XCD mapping: all 16 tiles of a batch on one XCD.
// ---------------------------------------------------------------------------
__global__ __launch_bounds__(512, 4) void gram_mfma(const unsigned short* __restrict__ xh,
                                                    const unsigned short* __restrict__ xl,
                                                    float* __restrict__ G) {
  const int l = blockIdx.x;
  const int xcd = l & 7, seq = l >> 3;
  const int b = xcd + 8 * (seq >> 4);       // 4 batch-groups per XCD
  const int tile = seq & 15;
  const int i0 = (tile >> 2) * 128, j0 = (tile & 3) * 128;

  const unsigned short* __restrict__ Fh = xh + (size_t)b * C * N;
  const unsigned short* __restrict__ Fl = xl + (size_t)b * C * N;
  float* __restrict__ Gb = G + (size_t)b * C * C;

  __shared__ __align__(16) unsigned short Ah[128 * 64], Al[128 * 64],
                                          Bh[128 * 64], Bl[128 * 64];  // 64 KB

  const int t = threadIdx.x, wave = t >> 6, lane = t & 63;
  const int wi = wave >> 1, wj = wave & 1;     // 4x2 wave grid
  const int lrow = lane & 15, quad = lane >> 4;
  const int srow8 = lane >> 3;                 // row within 8-row staging chunk
  const int sel = ((lane & 7) ^ srow8) * 8;    // swizzled k-elem source offset

  f32x4 acc[2][4] = {};

  for (int k0 = 0; k0 < N; k0 += 64) {
    __syncthreads();
#pragma unroll
    for (int cc = 0; cc < 2; ++cc) {
      const int chunk = wave * 2 + cc;         // 16 chunks of 8 rows
      const int row = chunk * 8 + srow8;
      const size_t gA = (size_t)(i0 + row) * N + k0 + sel;
      const size_t gB = (size_t)(j0 + row) * N + k0 + sel;
      glds16(Fh + gA, &Ah[chunk * 512]);
      glds16(Fl + gA, &Al[chunk * 512]);
      glds16(Fh + gB, &Bh[chunk * 512]);
      glds16(Fl + gB, &Bl[chunk * 512]);
    }
    __syncthreads();

#pragma unroll
    for (int kh = 0; kh < 2; ++kh) {
      s16x8 ah[2], al[2], bh[4], bl[4];
#pragma unroll
      for (int ti = 0; ti < 2; ++ti) {
        const int r = wi * 32 + ti * 16 + lrow;
        const int off = r * 64 + ((kh * 4 + quad) ^ (r & 7)) * 8;
        ah[ti] = *(const s16x8*)&Ah[off];
        al[ti] = *(const s16x8*)&Al[off];
      }
#pragma unroll
      for (int tj = 0; tj < 4; ++tj) {
        const int r = wj * 64 + tj * 16 + lrow;
        const int off = r * 64 + ((kh * 4 + quad) ^ (r & 7)) * 8;
        bh[tj] = *(const s16x8*)&Bh[off];
        bl[tj] = *(const s16x8*)&Bl[off];
      }
#pragma unroll
      for (int ti = 0; ti < 2; ++ti)
#pragma unroll
        for (int tj = 0; tj < 4; ++tj) {
          acc[ti][tj] = __builtin_amdgcn_mfma_f32_16x16x32_bf16(ah[ti], bh[tj], acc[ti][tj], 0, 0, 0);
          acc[ti][tj] = __builtin_amdgcn_mfma_f32_16x16x32_bf16(ah[ti], bl[tj], acc[ti][tj], 0, 0, 0);
          acc[ti][tj] = __builtin_amdgcn_mfma_f32_16x16x32_bf16(al[ti], bh[tj], acc[ti][tj], 0, 0, 0);
        }
    }
  }

  // C/D layout: col = lane&15, row = quad*4 + reg  [measured m89]
#pragma unroll
  for (int ti = 0; ti < 2; ++ti) {
    const int gr0 = i0 + wi * 32 + ti * 16 + quad * 4;
#pragma unroll
    for (int tj = 0; tj < 4; ++tj) {
      const int gc = j0 + wj * 64 + tj * 16 + lrow;
#pragma unroll
      for (int r = 0; r < 4; ++r)
        Gb[(size_t)(gr0 + r) * C + gc] = acc[ti][tj][r];
    }
  }
}

// ---------------------------------------------------------------------------
// Kernel 2: row softmax of (rowmax - G) == exp(rowmin - G)/sum, output bf16.
// ---------------------------------------------------------------------------
__global__ __launch_bounds__(256) void softmax_kernel(const float* __restrict__ G,
                                                      unsigned short* __restrict__ A) {
  const int t = threadIdx.x;
  const int r = t >> 7;
  const int c = t & 127;
  const size_t row = (size_t)blockIdx.x * 2 + r;

  const float4 v = *(const float4*)&G[row * C + c * 4];
  float mn = fminf(fminf(v.x, v.y), fminf(v.z, v.w));
#pragma unroll
  for (int o = 32; o > 0; o >>= 1) mn = fminf(mn, __shfl_xor(mn, o, 64));

  __shared__ float redmin[4], redsum[4];
  const int w = t >> 6;
  if ((t & 63) == 0) redmin[w] = mn;
  __syncthreads();
  mn = fminf(redmin[r * 2], redmin[r * 2 + 1]);

  const float e0 = __expf(mn - v.x), e1 = __expf(mn - v.y);
  const float e2 = __expf(mn - v.z), e3 = __expf(mn - v.w);
  float s = e0 + e1 + e2 + e3;
#pragma unroll
  for (int o = 32; o > 0; o >>= 1) s += __shfl_xor(s, o, 64);
  if ((t & 63) == 0) redsum[w] = s;
  __syncthreads();
  s = redsum[r * 2] + redsum[r * 2 + 1];

  const float inv = 1.0f / s;
  u16x4 o4;
  o4[0] = f32_to_bf16(e0 * inv); o4[1] = f32_to_bf16(e1 * inv);
  o4[2] = f32_to_bf16(e2 * inv); o4[3] = f32_to_bf16(e3 * inv);
  *(u16x4*)&A[row * C + c * 4] = o4;
}

// ---------------------------------------------------------------------------
// Kernel 3: E = A*F (bf16 MFMA), out = beta*E + x.
// 128x128 tile, BK=64, 256 threads (4 waves 2x2, each 64x64 = 4x4 MFMA).
// Same XOR source swizzle. Epilogue: per-wave LDS transpose -> float4 I/O.
// ---------------------------------------------------------------------------
__global__ __launch_bounds__(256, 4) void av_mfma(const unsigned short* __restrict__ Abf,
                                                  const unsigned short* __restrict__ xhT,
                                                  const float* __restrict__ x,
                                                  const float* __restrict__ beta,
                                                  float* __restrict__ out) {
  const int l = blockIdx.x;
  const int xcd = l & 7, seq = l >> 3;
  const int b = xcd + 8 * (seq >> 5);       // 4 batch-groups per XCD
  const int tile = seq & 31;
  const int i0 = (tile >> 3) * 128;         // over C (4)
  const int j0 = (tile & 7) * 128;          // over N (8)

  const unsigned short* __restrict__ Ab = Abf + (size_t)b * C * C;
  const unsigned short* __restrict__ FT = xhT + (size_t)b * N * C;
  const float* __restrict__ xb = x + (size_t)b * C * N;
  float* __restrict__ ob = out + (size_t)b * C * N;

  __shared__ __align__(16) unsigned short SMEM[2 * 128 * 64];   // 32 KB
  unsigned short* As = SMEM;
  unsigned short* Bs = SMEM + 128 * 64;

  const int t = threadIdx.x, wave = t >> 6, lane = t & 63;
  const int wi = wave >> 1, wj = wave & 1;
  const int lrow = lane & 15, quad = lane >> 4;
  const int srow8 = lane >> 3;
  const int sel = ((lane & 7) ^ srow8) * 8;

  f32x4 acc[4][4] = {};

  for (int k0 = 0; k0 < C; k0 += 64) {
    __syncthreads();
#pragma unroll
    for (int cc = 0; cc < 4; ++cc) {
      const int chunk = wave * 4 + cc;
      const int row = chunk * 8 + srow8;
      glds16(Ab + (size_t)(i0 + row) * C + k0 + sel, &As[chunk * 512]);
      glds16(FT + (size_t)(j0 + row) * C + k0 + sel, &Bs[chunk * 512]);
    }
    __syncthreads();

#pragma unroll
    for (int kh = 0; kh < 2; ++kh) {
      s16x8 af[4], bf[4];
#pragma unroll
      for (int ti = 0; ti < 4; ++ti) {
        const int r = wi * 64 + ti * 16 + lrow;
        af[ti] = *(const s16x8*)&As[r * 64 + ((kh * 4 + quad) ^ (r & 7)) * 8];
      }
#pragma unroll
      for (int tj = 0; tj < 4; ++tj) {
        const int r = wj * 64 + tj * 16 + lrow;
        bf[tj] = *(const s16x8*)&Bs[r * 64 + ((kh * 4 + quad) ^ (r & 7)) * 8];
      }
#pragma unroll
      for (int ti = 0; ti < 4; ++ti)
#pragma unroll
        for (int tj = 0; tj < 4; ++tj)
          acc[ti][tj] = __builtin_amdgcn_mfma_f32_16x16x32_bf16(af[ti], bf[tj], acc[ti][tj], 0, 0, 0);
    }
  }

  // Epilogue: per-wave LDS transpose of each 16x64 strip, then float4 I/O.
  __syncthreads();
  float* fs = (float*)SMEM + wave * 1024;   // 4 KB per wave
  const float bv = beta[0];
#pragma unroll
  for (int ti = 0; ti < 4; ++ti) {
#pragma unroll
    for (int tj = 0; tj < 4; ++tj)
#pragma unroll
      for (int r = 0; r < 4; ++r)
        fs[(quad * 4 + r) * 64 + tj * 16 + lrow] = acc[ti][tj][r];
    __syncthreads();
#pragma unroll
    for (int p = 0; p < 4; ++p) {
      const int f = p * 64 + lane;           // float4 index within 16x64 strip
      const int rr = f >> 4, cc4 = (f & 15) * 4;
      const f32x4 e = *(const f32x4*)&fs[rr * 64 + cc4];
      const int gr = i0 + wi * 64 + ti * 16 + rr;
      const int gc = j0 + wj * 64 + cc4;
      const size_t o = (size_t)gr * N + gc;
      const float4 xv = *(const float4*)&xb[o];
      float4 ov;
      ov.x = fmaf(bv, e[0], xv.x);
      ov.y = fmaf(bv, e[1], xv.y);
      ov.z = fmaf(bv, e[2], xv.z);
      ov.w = fmaf(bv, e[3], xv.w);
      *(float4*)&ob[o] = ov;
    }
    __syncthreads();
  }
}

// ---------------------------------------------------------------------------
extern "C" void kernel_launch(void* const* d_in, const int* in_sizes, int n_in,
                              void* d_out, int out_size, void* d_ws, size_t ws_size,
                              hipStream_t stream) {
  const float* x    = (const float*)d_in[0];
  const float* beta = (const float*)d_in[1];
  float* out = (float*)d_out;

  char* ws = (char*)d_ws;
  float* G            = (float*)ws;          ws += (size_t)B * C * C * 4;  // 32 MB
  unsigned short* xh  = (unsigned short*)ws; ws += (size_t)B * C * N * 2;  // 32 MB
  unsigned short* xl  = (unsigned short*)ws; ws += (size_t)B * C * N * 2;  // 32 MB
  unsigned short* xhT = (unsigned short*)ws; ws += (size_t)B * N * C * 2;  // 32 MB
  unsigned short* Abf = (unsigned short*)ws;                               // 16 MB

  convert_kernel<<<dim3(N / 64, C / 64, B), dim3(256), 0, stream>>>(x, xh, xl, xhT);
  gram_mfma     <<<dim3(512),               dim3(512), 0, stream>>>(xh, xl, G);
  softmax_kernel<<<dim3(B * C / 2),         dim3(256), 0, stream>>>(G, Abf);
  av_mfma       <<<dim3(1024),              dim3(256), 0, stream>>>(Abf, xhT, x, beta, out);
}